// Round 10
// baseline (66.725 us; speedup 1.0000x reference)
//
#include <hip/hip_runtime.h>

#define N_POINTS 204800
#define N_GT 256
#define BLOCK 1024           // 16 waves
#define GRID 512             // 2 blocks/CU -> 32 waves/CU (hardware max)
#define PTS_PER_BLOCK 400
#define NF4 (N_POINTS / 2)   // total float4 count in points array (102400)

typedef float v2f __attribute__((ext_vector_type(2)));

__device__ __forceinline__ v2f pk_fma(v2f a, v2f b, v2f c) {
  return __builtin_elementwise_fma(a, b, c);
}
__device__ __forceinline__ v2f lohalf(float4 q) { return (v2f){q.x, q.y}; }
__device__ __forceinline__ v2f hihalf(float4 q) { return (v2f){q.z, q.w}; }

// Math (R1-R9): per box, centerness^2 = max(fx,0)*fy under a >=0 max-reduce
// (one-clamp), fx/fy quadratics in px/py (division folded into coefficients),
// sqrt hoisted out of the 256-box max. Coef 24B/box, x/y-interleaved so every
// v2f operand is an even-aligned half of a broadcast ds_read_b128.
//
// R10: occupancy attack. R5-R9 all ran 16 waves/CU with no co-resident block
// to cover prologue/epilogue/barrier phases; five structural variants tied at
// ~65.7-67.6 total. Now: 512 blocks x 16 waves, 400 pts/block, 2-box coef
// groups (12 VGPR held), pt[4]+acc[8] -> ~50 VGPR, __launch_bounds__(1024,8)
// forces <=64 VGPR so TWO blocks co-reside (32 waves/CU). Block pairs overlap
// each other's non-loop phases; loop LDS/CU (9.2 kcyc) stays under VALU.
__global__ __launch_bounds__(BLOCK, 8) void centerness_kernel(
    const float* __restrict__ points, const float* __restrict__ gt,
    float* __restrict__ out) {
  __shared__ float scoef[6 * N_GT];               // 6144 B
  __shared__ float spart[16 * PTS_PER_BLOCK];     // 25600 B (total 31744)

  const int t = threadIdx.x;
  const int lane = t & 63;
  const int w = t >> 6;  // wave id = 16-box chunk id

  // --- load this block's 400 points: 200 float4 = 3 full rounds + 8 extra ---
  const int pbase = blockIdx.x * 200;  // float4 index of block start
  const float4* p4 = (const float4*)points;
  float4 pt[4];
#pragma unroll
  for (int it = 0; it < 3; ++it) pt[it] = p4[pbase + it * 64 + lane];
  {
    int idx = pbase + 192 + lane;      // valid only for lane<8
    if (idx > NF4 - 1) idx = NF4 - 1;  // clamp: garbage is write-guarded
    pt[3] = p4[idx];
  }

  // --- stage coefficients (threads 0..255, one box each) ---
  if (t < N_GT) {
    float4 b = ((const float4*)gt)[t];  // x1,y1,x2,y2
    float iw = 1.0f / (b.z - b.x);
    float ih = 1.0f / (b.w - b.y);
    float* c = &scoef[6 * t];
    c[0] = -iw;               c[1] = -ih;
    c[2] = (b.x + b.z) * iw;  c[3] = (b.y + b.w) * ih;
    c[4] = -(b.x * b.z) * iw; c[5] = -(b.y * b.w) * ih;
  }
  __syncthreads();

  float acc[8];
#pragma unroll
  for (int k = 0; k < 8; ++k) acc[k] = 0.f;

  const float4* cw = (const float4*)scoef + w * 24;  // 16 boxes * 6 f / 4

#pragma unroll 1
  for (int g = 0; g < 8; ++g) {
    // 2 boxes = 3 uniform (broadcast) b128 reads, held for the point sweep.
    float4 q0 = cw[3 * g + 0];
    float4 q1 = cw[3 * g + 1];
    float4 q2 = cw[3 * g + 2];
    // box0: a2=lo(q0) a1=hi(q0) a0=lo(q1); box1: a2=hi(q1) a1=lo(q2) a0=hi(q2)
    v2f c0a = lohalf(q0), c0b = hihalf(q0), c0c = lohalf(q1);
    v2f c1a = hihalf(q1), c1b = lohalf(q2), c1c = hihalf(q2);

#pragma unroll
    for (int it = 0; it < 4; ++it) {
      v2f P0 = lohalf(pt[it]);
      v2f P1 = hihalf(pt[it]);
      {
        v2f r0 = pk_fma(pk_fma(c0a, P0, c0b), P0, c0c);
        v2f r1 = pk_fma(pk_fma(c1a, P0, c1b), P0, c1c);
        float v0 = fmaxf(r0.x, 0.f) * r0.y;
        float v1 = fmaxf(r1.x, 0.f) * r1.y;
        acc[2 * it] = fmaxf(fmaxf(acc[2 * it], v0), v1);  // v_max3
      }
      {
        v2f r0 = pk_fma(pk_fma(c0a, P1, c0b), P1, c0c);
        v2f r1 = pk_fma(pk_fma(c1a, P1, c1b), P1, c1c);
        float v0 = fmaxf(r0.x, 0.f) * r0.y;
        float v1 = fmaxf(r1.x, 0.f) * r1.y;
        acc[2 * it + 1] = fmaxf(fmaxf(acc[2 * it + 1], v0), v1);
      }
    }
  }

  // --- dump per-wave partials: spart[w][pid], pid = it*128 + 2*lane (+1) ---
#pragma unroll
  for (int it = 0; it < 3; ++it) {
    float2* row = (float2*)&spart[w * PTS_PER_BLOCK + it * 128];
    row[lane] = make_float2(acc[2 * it], acc[2 * it + 1]);
  }
  if (lane < 8) {  // it=3: only 16 valid points (384..399)
    float2* row = (float2*)&spart[w * PTS_PER_BLOCK + 384];
    row[lane] = make_float2(acc[6], acc[7]);
  }
  __syncthreads();

  // --- 16-way max reduce: thread t owns point t (t < 400) ---
  if (t < PTS_PER_BLOCK) {
    float m = spart[t];
#pragma unroll
    for (int i = 1; i < 16; ++i) m = fmaxf(m, spart[i * PTS_PER_BLOCK + t]);
    out[blockIdx.x * PTS_PER_BLOCK + t] = sqrtf(m);
  }
}

extern "C" void kernel_launch(void* const* d_in, const int* in_sizes, int n_in,
                              void* d_out, int out_size, void* d_ws, size_t ws_size,
                              hipStream_t stream) {
  const float* points = (const float*)d_in[0];     // (204800, 2)
  const float* gt_bboxes = (const float*)d_in[1];  // (256, 4)
  // d_in[2] strides: unused by the reference output.
  float* out = (float*)d_out;                      // (204800,)

  centerness_kernel<<<GRID, BLOCK, 0, stream>>>(points, gt_bboxes, out);
}

// Round 11
// 66.471 us; speedup vs baseline: 1.0038x; 1.0038x over previous
//
#include <hip/hip_runtime.h>

#define N_POINTS 204800
#define N_GT 256
#define NCELL 256           // 16 x 16 cells of 64 px over the 1024^2 image

// R11: spatial pruning. R5-R10 (six structural variants: occupancy, balance,
// pk-fma, pipelining, loop inversion) all tied at ~66 +/- 1 total -> the
// all-256-box VALU floor itself is the wall. But boxes are 16-256 px in a
// 1024 image: a point is inside only ~4-5 boxes; every other box contributes
// an exact 0 (clamped). Cell lists make the work proportional to overlap.
//
// Exactness: point p lies in cell C(p); if a box fails the CLOSED overlap
// test vs C(p), then p is strictly outside the box in x or y, so
// max(l,0)max(r,0) or max(t,0)max(b,0) is exactly 0 = the pruned value.
//
// Kernel A: block = cell; 64 lanes x 4 rounds test boxes, ballot-compact ids
// (u8) into d_ws. Kernel B: 1 point/thread; stage quadratic coefficients
// (R1-R10 math: fx = a2*px^2+a1*px+a0 with the l+r division folded in; sqrt
// hoisted out of the max; one-clamp max(fx,0)*fy under >=0 max-reduce) in
// 8 KB LDS; walk the lane's cell list with u8-id gather reads.

__global__ __launch_bounds__(64) void build_lists_kernel(
    const float* __restrict__ gt, int* __restrict__ cnts,
    unsigned char* __restrict__ ids) {
  const int cell = blockIdx.x;   // 0..255
  const int lane = threadIdx.x;  // 0..63
  const float clx = (float)((cell & 15) * 64);
  const float chx = clx + 64.0f;
  const float cly = (float)((cell >> 4) * 64);
  const float chy = cly + 64.0f;

  unsigned char* dst = ids + cell * 256;
  int base = 0;
#pragma unroll
  for (int q = 0; q < 4; ++q) {
    int b = q * 64 + lane;
    float4 bx = ((const float4*)gt)[b];  // x1,y1,x2,y2 (L2-broadcast, 4 KB)
    // closed (conservative) box-cell overlap
    bool hit = (bx.x <= chx) && (bx.z >= clx) && (bx.y <= chy) && (bx.w >= cly);
    unsigned long long m = __ballot(hit);
    int pre = __popcll(m & ((1ull << lane) - 1ull));
    if (hit) dst[base + pre] = (unsigned char)b;
    base += __popcll(m);
  }
  if (lane == 0) cnts[cell] = base;
}

__global__ __launch_bounds__(256) void centerness_kernel(
    const float* __restrict__ points, const float* __restrict__ gt,
    const int* __restrict__ cnts, const unsigned char* __restrict__ ids,
    float* __restrict__ out) {
  __shared__ float4 sc[2 * N_GT];  // 32B/box: [2b]=(a2x,a1x,a0x,-), [2b+1]=y

  const int t = threadIdx.x;
  const int i = blockIdx.x * 256 + t;
  float2 p = ((const float2*)points)[i];

  // stage coefficients: thread t = box t
  {
    float4 b = ((const float4*)gt)[t];
    float iw = 1.0f / (b.z - b.x);
    float ih = 1.0f / (b.w - b.y);
    sc[2 * t]     = make_float4(-iw, (b.x + b.z) * iw, -(b.x * b.z) * iw, 0.f);
    sc[2 * t + 1] = make_float4(-ih, (b.y + b.w) * ih, -(b.y * b.w) * ih, 0.f);
  }

  // cell id (px,py in [0,1024); clamp guards the exact-1024 corner anyway)
  int cx = (int)(p.x * 0.015625f); cx = cx > 15 ? 15 : cx;
  int cy = (int)(p.y * 0.015625f); cy = cy > 15 ? 15 : cy;
  const int cell = cy * 16 + cx;
  const int cnt = cnts[cell];  // global, L2-hot (issued before the barrier)
  const unsigned char* lst = ids + cell * 256;

  __syncthreads();

  float acc = 0.0f;
  for (int k = 0; k < cnt; k += 4) {
    // 4 ids at a time; slots past cnt hold poison but ids are <256 so the
    // gathered coefficients are valid memory and the update is predicated.
    uchar4 id4 = *(const uchar4*)(lst + k);
    int rem = cnt - k;  // >= 1
#pragma unroll
    for (int u = 0; u < 4; ++u) {
      int b = (int)(&id4.x)[u];
      float4 cxv = sc[2 * b];      // per-lane ds_read_b128 gather
      float4 cyv = sc[2 * b + 1];
      float fx = fmaf(fmaf(cxv.x, p.x, cxv.y), p.x, cxv.z);
      float fy = fmaf(fmaf(cyv.x, p.y, cyv.y), p.y, cyv.z);
      float v = fmaxf(fx, 0.f) * fy;  // one-clamp: v<=0 when outside
      if (u < rem) acc = fmaxf(acc, v);
    }
  }
  out[i] = sqrtf(acc);
}

extern "C" void kernel_launch(void* const* d_in, const int* in_sizes, int n_in,
                              void* d_out, int out_size, void* d_ws, size_t ws_size,
                              hipStream_t stream) {
  const float* points = (const float*)d_in[0];     // (204800, 2)
  const float* gt_bboxes = (const float*)d_in[1];  // (256, 4)
  // d_in[2] strides: unused by the reference output.
  float* out = (float*)d_out;                      // (204800,)

  int* cnts = (int*)d_ws;                               // 256 ints (1 KB)
  unsigned char* ids = (unsigned char*)d_ws + 1024;     // 256 cells x 256 (64 KB)

  build_lists_kernel<<<NCELL, 64, 0, stream>>>(gt_bboxes, cnts, ids);
  centerness_kernel<<<N_POINTS / 256, 256, 0, stream>>>(points, gt_bboxes,
                                                        cnts, ids, out);
}